// Round 6
// baseline (737.429 us; speedup 1.0000x reference)
//
#include <hip/hip_runtime.h>
#include <hip/hip_bf16.h>

#define BATCH 256
#define TSTEPS 1024
#define NIN 128
#define NL 64
#define NH 128
#define NOUT 32

typedef __attribute__((ext_vector_type(8))) short short8;
typedef __attribute__((ext_vector_type(4))) float f32x4;

__device__ inline int pk2(float x, float y) {
    __hip_bfloat162 h = __float22bfloat162_rn(make_float2(x, y));
    union { __hip_bfloat162 h; int i; } u;
    u.h = h;
    return u.i;
}
__device__ inline short bf1(float x) {
    __hip_bfloat16 h = __float2bfloat16(x);
    union { __hip_bfloat16 h; short s; } u;
    u.h = h;
    return u.s;
}

#define WG_BARRIER() asm volatile("s_waitcnt lgkmcnt(0)\n\ts_barrier" ::: "memory")
#define WAVE_LDS_FENCE() asm volatile("s_waitcnt lgkmcnt(0)" ::: "memory")

// ---------------------------------------------------------------------------
// Pass 1: u'[b][t][l] = bf16( C[l,:]·s[b,t,:] + h1[l] )
// MFMA GEMM. A = C (latent x input) static frags; B = s rows global->VGPR
// (1-iter prefetch). D frags -> per-wave LDS transpose (16x33-dword rows,
// conflict-free) -> one contiguous 2KB dwordx4-coalesced store per iter.
// Grid: 512 WGs x 256 thr; each wave: 8 iters x 16 rows.
// ---------------------------------------------------------------------------
__launch_bounds__(256, 1)
__global__ void ugemm_mfma(const float* __restrict__ input,
                           const float* __restrict__ C,
                           const float* __restrict__ h1,
                           unsigned short* __restrict__ u16) {
    __shared__ int tbuf[4][16 * 33];   // per-wave transpose buffer (2112 B)

    const int lane = threadIdx.x & 63;
    const int wv   = threadIdx.x >> 6;
    const int c = lane & 15;
    const int q = lane >> 4;
    int* tb = tbuf[wv];
    const long wbase = ((long)blockIdx.x * 4 + wv) * 128;  // first row (b*1024+t)

    // static A-frags: cA[mt][kf] = C[(mt*16+c), kf*32+q*8 .. +7] bf16
    short8 cA[4][4];
    #pragma unroll
    for (int mt = 0; mt < 4; ++mt)
        #pragma unroll
        for (int kf = 0; kf < 4; ++kf) {
            const float* p = C + (mt * 16 + c) * NIN + kf * 32 + q * 8;
            float4 r0 = *(const float4*)p;
            float4 r1 = *(const float4*)(p + 4);
            union { short8 s; int i[4]; } f;
            f.i[0] = pk2(r0.x, r0.y); f.i[1] = pk2(r0.z, r0.w);
            f.i[2] = pk2(r1.x, r1.y); f.i[3] = pk2(r1.z, r1.w);
            cA[mt][kf] = f.s;
        }
    f32x4 h1f[4];
    #pragma unroll
    for (int mt = 0; mt < 4; ++mt)
        h1f[mt] = *(const f32x4*)(h1 + mt * 16 + q * 4);

    // prefetch it=0 raw rows
    float4 raw[8], rawn[8];
    {
        const float* sr = input + (wbase + c) * NIN;
        #pragma unroll
        for (int kf = 0; kf < 4; ++kf) {
            raw[2*kf]   = *(const float4*)(sr + kf * 32 + q * 8);
            raw[2*kf+1] = *(const float4*)(sr + kf * 32 + q * 8 + 4);
        }
    }

    const int rrd = lane >> 2;       // LDS-read row (0..15)
    const int ord = lane & 3;        // LDS-read chunk (0..3)

    for (int it = 0; it < 8; ++it) {
        if (it < 7) {
            const float* sr = input + (wbase + (it + 1) * 16 + c) * NIN;
            #pragma unroll
            for (int kf = 0; kf < 4; ++kf) {
                rawn[2*kf]   = *(const float4*)(sr + kf * 32 + q * 8);
                rawn[2*kf+1] = *(const float4*)(sr + kf * 32 + q * 8 + 4);
            }
        }
        short8 bf[4];
        #pragma unroll
        for (int kf = 0; kf < 4; ++kf) {
            union { short8 s; int i[4]; } f;
            f.i[0] = pk2(raw[2*kf].x,   raw[2*kf].y);
            f.i[1] = pk2(raw[2*kf].z,   raw[2*kf].w);
            f.i[2] = pk2(raw[2*kf+1].x, raw[2*kf+1].y);
            f.i[3] = pk2(raw[2*kf+1].z, raw[2*kf+1].w);
            bf[kf] = f.s;
        }
        // MFMA: D[latent, t-row]; lane holds (t-row c, latents mt*16+q*4+e)
        #pragma unroll
        for (int mt = 0; mt < 4; ++mt) {
            f32x4 acc = __builtin_amdgcn_mfma_f32_16x16x32_bf16(cA[mt][0], bf[0], h1f[mt], 0, 0, 0);
            acc = __builtin_amdgcn_mfma_f32_16x16x32_bf16(cA[mt][1], bf[1], acc, 0, 0, 0);
            acc = __builtin_amdgcn_mfma_f32_16x16x32_bf16(cA[mt][2], bf[2], acc, 0, 0, 0);
            acc = __builtin_amdgcn_mfma_f32_16x16x32_bf16(cA[mt][3], bf[3], acc, 0, 0, 0);
            // transpose via LDS: row = t-row c (stride 33 dwords)
            *(int2*)&tb[c * 33 + mt * 8 + q * 2] =
                make_int2(pk2(acc[0], acc[1]), pk2(acc[2], acc[3]));
        }
        WAVE_LDS_FENCE();
        int4 v0 = *(int4*)&tb[rrd * 33 + ord * 8];
        int4 v1 = *(int4*)&tb[rrd * 33 + ord * 8 + 4];
        // coalesced store: 2KB contiguous block = rows wbase+it*16 .. +15
        unsigned int* gp = (unsigned int*)u16 + (size_t)(wbase + it * 16) * 32;
        *(int4*)(gp + lane * 8)     = v0;
        *(int4*)(gp + lane * 8 + 4) = v1;
        WAVE_LDS_FENCE();   // reads done before next iter's writes (scheduling)
        #pragma unroll
        for (int j = 0; j < 8; ++j) raw[j] = rawn[j];
    }
}

// ---------------------------------------------------------------------------
// Pass 2: MFMA scan, M-split over 4 waves, 16 WGs x 256 thr.
// LDS layout: 16B block j = (l>>3)*16 + c  ->  all b128 reads are per-quarter
// stride-1 (conflict-free); b64 writes 2-way (free).
// ---------------------------------------------------------------------------
__launch_bounds__(256, 1)
__global__ void plrnn_scan_mfma(const float* __restrict__ A,
                                const float* __restrict__ W1,
                                const float* __restrict__ W2,
                                const float* __restrict__ h2,
                                const unsigned short* __restrict__ u16,
                                const float* __restrict__ Wout,
                                const float* __restrict__ bout,
                                float* __restrict__ out) {
    __shared__ __attribute__((aligned(16))) int zb[8 * 16 * 4];    // 2 KB
    __shared__ __attribute__((aligned(16))) int hb[16 * 16 * 4];   // 4 KB

    const int lane = threadIdx.x & 63;
    const int w    = threadIdx.x >> 6;     // wave 0..3
    const int c = lane & 15;               // batch col
    const int q = lane >> 4;               // quad
    const int bbase = blockIdx.x * 16;

    // ---- static weight fragments ----
    short8 aw2[2][2];   // H tiles mt = 2w, 2w+1 ; K = 64 (2 frags)
    #pragma unroll
    for (int i = 0; i < 2; ++i)
        #pragma unroll
        for (int kt = 0; kt < 2; ++kt) {
            const float* p = W2 + ((2*w + i) * 16 + c) * NL + kt * 32 + q * 8;
            short8 f;
            #pragma unroll
            for (int j = 0; j < 8; ++j) f[j] = bf1(p[j]);
            aw2[i][kt] = f;
        }
    short8 aw1[4];      // Z tile lt = w ; K = 128 (4 frags)
    #pragma unroll
    for (int kt = 0; kt < 4; ++kt) {
        const float* p = W1 + (w * 16 + c) * NH + kt * 32 + q * 8;
        short8 f;
        #pragma unroll
        for (int j = 0; j < 8; ++j) f[j] = bf1(p[j]);
        aw1[kt] = f;
    }
    f32x4 h2f[2];
    #pragma unroll
    for (int i = 0; i < 2; ++i)
        h2f[i] = *(const f32x4*)(h2 + (2*w + i) * 16 + q * 4);
    const f32x4 af = *(const f32x4*)(A + w * 16 + q * 4);

    f32x4 zf = {0.f, 0.f, 0.f, 0.f};

    // u' layout [b][t][l]: lane (c,q,w) reads 8B at +t*64
    const unsigned short* ub =
        u16 + ((size_t)(bbase + c) * TSTEPS) * 64 + w * 16 + q * 4;
    int2 ucur = *(const int2*)ub;
    int2 unx  = *(const int2*)(ub + 64);

    // LDS block indices (precomputed)
    const int jz_w = ((2*w + (q >> 1)) * 16 + c) * 4 + (q & 1) * 2;  // z write
    const int jz_r0 = (q * 16 + c) * 4;             // bz0 (latents q*8..+7)
    const int jz_r1 = ((q + 4) * 16 + c) * 4;       // bz1 (latents 32+q*8..+7)

    for (int t = 0; t < TSTEPS; ++t) {
        // ---- publish z (wave w owns latents [16w,16w+16)) ----
        *(int2*)&zb[jz_w] = make_int2(pk2(zf[0], zf[1]), pk2(zf[2], zf[3]));
        WG_BARRIER();
        short8 bz0 = *(short8*)&zb[jz_r0];
        short8 bz1 = *(short8*)&zb[jz_r1];

        // prefetch u'(t+2) — stays in flight across both MFMA phases
        int tp = (t + 2 < TSTEPS) ? t + 2 : TSTEPS - 1;
        int2 upf = *(const int2*)(ub + (size_t)tp * 64);

        // ---- MFMA1: H rows [32w,32w+32) = relu(W2 @ Z + h2) ----
        #pragma unroll
        for (int i = 0; i < 2; ++i) {
            f32x4 acc = __builtin_amdgcn_mfma_f32_16x16x32_bf16(aw2[i][0], bz0, h2f[i], 0, 0, 0);
            acc = __builtin_amdgcn_mfma_f32_16x16x32_bf16(aw2[i][1], bz1, acc, 0, 0, 0);
            int jh = (((2*w + i) * 2 + (q >> 1)) * 16 + c) * 4 + (q & 1) * 2;
            *(int2*)&hb[jh] =
                make_int2(pk2(fmaxf(acc[0], 0.f), fmaxf(acc[1], 0.f)),
                          pk2(fmaxf(acc[2], 0.f), fmaxf(acc[3], 0.f)));
        }
        WG_BARRIER();
        short8 bh0 = *(short8*)&hb[((0 * 4 + q) * 16 + c) * 4];
        short8 bh1 = *(short8*)&hb[((1 * 4 + q) * 16 + c) * 4];
        short8 bh2 = *(short8*)&hb[((2 * 4 + q) * 16 + c) * 4];
        short8 bh3 = *(short8*)&hb[((3 * 4 + q) * 16 + c) * 4];

        // ---- MFMA2: Z' rows [16w,16w+16) = clip(A.z + u' + W1 @ H) ----
        f32x4 cin;
        cin[0] = fmaf(zf[0], af[0], __int_as_float(ucur.x << 16));
        cin[1] = fmaf(zf[1], af[1], __int_as_float(ucur.x & 0xffff0000));
        cin[2] = fmaf(zf[2], af[2], __int_as_float(ucur.y << 16));
        cin[3] = fmaf(zf[3], af[3], __int_as_float(ucur.y & 0xffff0000));
        f32x4 acc = __builtin_amdgcn_mfma_f32_16x16x32_bf16(aw1[0], bh0, cin, 0, 0, 0);
        acc = __builtin_amdgcn_mfma_f32_16x16x32_bf16(aw1[1], bh1, acc, 0, 0, 0);
        acc = __builtin_amdgcn_mfma_f32_16x16x32_bf16(aw1[2], bh2, acc, 0, 0, 0);
        acc = __builtin_amdgcn_mfma_f32_16x16x32_bf16(aw1[3], bh3, acc, 0, 0, 0);
        #pragma unroll
        for (int e = 0; e < 4; ++e)
            zf[e] = fminf(fmaxf(acc[e], -5.f), 5.f);
        ucur = unx;
        unx  = upf;
    }

    // ---- epilogue: out = Wout @ Z + bout (waves 0,1) ----
    *(int2*)&zb[jz_w] = make_int2(pk2(zf[0], zf[1]), pk2(zf[2], zf[3]));
    WG_BARRIER();
    if (w < 2) {
        short8 fz0 = *(short8*)&zb[jz_r0];
        short8 fz1 = *(short8*)&zb[jz_r1];
        const float* p0 = Wout + (w * 16 + c) * NL + q * 8;
        const float* p1 = p0 + 32;
        short8 fa, fb;
        #pragma unroll
        for (int j = 0; j < 8; ++j) { fa[j] = bf1(p0[j]); fb[j] = bf1(p1[j]); }
        f32x4 cb = *(const f32x4*)(bout + w * 16 + q * 4);
        f32x4 acc = __builtin_amdgcn_mfma_f32_16x16x32_bf16(fa, fz0, cb, 0, 0, 0);
        acc = __builtin_amdgcn_mfma_f32_16x16x32_bf16(fb, fz1, acc, 0, 0, 0);
        *(f32x4*)&out[(bbase + c) * 32 + w * 16 + q * 4] = acc;
    }
}

extern "C" void kernel_launch(void* const* d_in, const int* in_sizes, int n_in,
                              void* d_out, int out_size, void* d_ws, size_t ws_size,
                              hipStream_t stream) {
    const float* input = (const float*)d_in[0];
    const float* A     = (const float*)d_in[1];
    const float* W1    = (const float*)d_in[2];
    const float* W2    = (const float*)d_in[3];
    const float* h1    = (const float*)d_in[4];
    const float* h2    = (const float*)d_in[5];
    const float* C     = (const float*)d_in[6];
    const float* Wout  = (const float*)d_in[7];
    const float* bout  = (const float*)d_in[8];
    float* out = (float*)d_out;

    unsigned short* u16 = (unsigned short*)d_ws;   // 256*1024*64 bf16 = 33.5 MB

    ugemm_mfma<<<dim3(512), dim3(256), 0, stream>>>(input, C, h1, u16);
    plrnn_scan_mfma<<<dim3(16), dim3(256), 0, stream>>>(
        A, W1, W2, h2, u16, Wout, bout, out);
}